// Round 21
// baseline (97.123 us; speedup 1.0000x reference)
//
#include <hip/hip_runtime.h>
#include <cstdint>
#include <math.h>

#define N_     8192
#define D_     256
#define NLBL   128
#define TEMP_INV 14.285714285714286f
#define HARDK  10
#define THETA  0.16f
#define GCAP   256              // per-label list capacity (mean 64, max ~104)

#define NCHUNK 64
#define CHUNK  (N_ / NCHUNK)    // 128 cols per chunk
#define TILES  (CHUNK / 32)     // 4
#define CSLOT  8                // per-(row,chunk): kg0 fills front, kg1 fills back
#define NTRI   ((NCHUNK * (NCHUNK + 1)) / 2)   // 2080 = 8 * 260

typedef __attribute__((ext_vector_type(8)))  short bf16x8;
typedef __attribute__((ext_vector_type(16))) float f32x16;

// ---------------- Threefry-2x32, key=(0,42): exact-match validated R1-R20 ----------------
__device__ __forceinline__ uint32_t rotl32(uint32_t x, int n) {
  return (x << n) | (x >> (32 - n));
}
__device__ uint32_t tf_bits(uint32_t idx) {
  uint32_t x0 = 0u, x1 = idx;
  const uint32_t k0 = 0u, k1 = 42u;
  const uint32_t k2 = k0 ^ k1 ^ 0x1BD11BDAu;
  x0 += k0; x1 += k1;
#define TFR(r) { x0 += x1; x1 = rotl32(x1, r); x1 ^= x0; }
  TFR(13) TFR(15) TFR(26) TFR(6)
  x0 += k1; x1 += k2 + 1u;
  TFR(17) TFR(29) TFR(16) TFR(24)
  x0 += k2; x1 += k0 + 2u;
  TFR(13) TFR(15) TFR(26) TFR(6)
  x0 += k0; x1 += k1 + 3u;
  TFR(17) TFR(29) TFR(16) TFR(24)
  x0 += k1; x1 += k2 + 4u;
  TFR(13) TFR(15) TFR(26) TFR(6)
  x0 += k2; x1 += k0 + 5u;
#undef TFR
  return x0 ^ x1;
}

__device__ __forceinline__ uint32_t f2bf(float x) {  // RNE
  uint32_t b = __float_as_uint(x);
  return (b + 0x7FFFu + ((b >> 16) & 1u)) >> 16;
}

// ---------------- K1: fused prep (512 blocks x 16 rows) + group masks (128 blocks) -----
__global__ __launch_bounds__(256) void prep_group_kernel(
    const float* __restrict__ feats, const int* __restrict__ labels,
    float* __restrict__ inv_norm, unsigned short* __restrict__ zt,
    uint32_t* __restrict__ mask_g, int* __restrict__ glist, int* __restrict__ cnt_g) {
  __shared__ uint4 tile[16][33];   // bf16 rows staged for transpose (+pad)
  __shared__ int lcnt;
  const int tid = threadIdx.x;

  if (blockIdx.x < 512) {
    const int row0 = blockIdx.x * 16;
    const int wv = tid >> 6, l = tid & 63;
#pragma unroll
    for (int rr = 0; rr < 4; ++rr) {
      const int rloc = wv * 4 + rr;
      const int row = row0 + rloc;
      float4 v = ((const float4*)feats)[(size_t)row * 64 + l];
      float ss = v.x * v.x + v.y * v.y + v.z * v.z + v.w * v.w;
#pragma unroll
      for (int o = 32; o; o >>= 1) ss += __shfl_xor(ss, o);
      float inv = 1.0f / fmaxf(sqrtf(ss), 1e-12f);
      if (l == 0) inv_norm[row] = inv;
      uint2 p;
      p.x = f2bf(v.x * inv) | (f2bf(v.y * inv) << 16);
      p.y = f2bf(v.z * inv) | (f2bf(v.w * inv) << 16);
      *(uint2*)((char*)&tile[0][0] + rloc * 528 + l * 8) = p;
    }
    __syncthreads();
#pragma unroll
    for (int it = 0; it < 2; ++it) {
      int idx = it * 256 + tid;          // 0..511
      int c = idx >> 4, r = idx & 15;    // consecutive tid -> consecutive r (256B seg)
      ((uint4*)zt)[(size_t)c * N_ + row0 + r] = tile[r][c];
    }
  } else {
    const int b = blockIdx.x - 512;
    const int lane = tid & 63, wv = tid >> 6;
    if (tid == 0) lcnt = 0;
    __syncthreads();
    for (int it = 0; it < N_; it += 256) {
      int col = it + tid;
      bool pred = (labels[col] == b);
      unsigned long long m = __ballot(pred);
      if (lane == 0) {
        int w0 = (it + wv * 64) >> 5;
        mask_g[b * 256 + w0]     = (uint32_t)m;
        mask_g[b * 256 + w0 + 1] = (uint32_t)(m >> 32);
      }
      if (pred) {
        int p = atomicAdd(&lcnt, 1);
        if (p < GCAP) glist[b * GCAP + p] = col;
      }
    }
    __syncthreads();
    if (tid == 0) cnt_g[b] = lcnt;
  }
}

// ---------------- K2: MFMA sim, triangle 128x128, NO staging, NO per-tile barriers -----
// The old LDS A-tile was a pure pass-through (lane l wrote slot l, read slot l).
// With 1 rowgroup, bf[16] = 64 VGPR fits resident (R15/R16: VGPR_Count=64, AGPR-parked),
// so each lane loads its A-fragment directly from zt (contiguous 512B per 32-lane half,
// L1-shared across the block's 4 waves). Waves run fully independent.
#define INS8(H0,H1,H2,H3,H4,H5,H6,H7,POS,C) \
  { H0 = (POS==0)?(C):H0; H1 = (POS==1)?(C):H1; H2 = (POS==2)?(C):H2; H3 = (POS==3)?(C):H3; \
    H4 = (POS==4)?(C):H4; H5 = (POS==5)?(C):H5; H6 = (POS==6)?(C):H6; H7 = (POS==7)?(C):H7; \
    ++POS; }

__global__ __launch_bounds__(256) void collect_kernel(const unsigned short* __restrict__ zt,
                                                      const int* __restrict__ labels,
                                                      const uint32_t* __restrict__ mask_g,
                                                      float* __restrict__ vals,
                                                      int* __restrict__ counts) {
  __shared__ float mcell[128 * 8];     // mirror slots [col][8], 4 KB
  __shared__ int   mcnt[128];          // mirror counters, 0.5 KB

  const int tid = threadIdx.x;
  const int l = tid & 63, wid = tid >> 6;  // wid 0..3
  const int kg = l >> 5;

  // bijective XCD swizzle: 2080 = 8 * 260; each XCD gets 260 consecutive triangle blocks
  const int bid = (blockIdx.x & 7) * (NTRI / 8) + (blockIdx.x >> 3);

  // triangular decode: bid -> (rc, cc), rc <= cc (block-uniform scalar loop)
  int rc = 0, rem = bid;
  while (rem >= NCHUNK - rc) { rem -= NCHUNK - rc; ++rc; }
  const int cc = rc + rem;
  const bool offdiag = (cc > rc);

  const int row0 = rc * 128;
  const int col0 = cc * CHUNK;
  const int rowW = row0 + wid * 32 + (l & 31);
  const int lab = labels[rowW];

  if (tid < 128) mcnt[tid] = 0;

  // 4 tile-masks preloaded
  uint32_t mW[TILES];
  {
    uint4 m0 = *(const uint4*)(mask_g + lab * 256 + (col0 >> 5));
    mW[0] = m0.x; mW[1] = m0.y; mW[2] = m0.z; mW[3] = m0.w;
  }

  const uint4* ztq = (const uint4*)zt;

  // B fragments from K-major planes: contiguous 512B per 32-lane half (AGPR-parked)
  bf16x8 bf[16];
#pragma unroll
  for (int kk = 0; kk < 16; ++kk)
    bf[kk] = *(const bf16x8*)&ztq[(size_t)(kk * 2 + kg) * N_ + rowW];

  // normal-path hit slots in registers (static select-chain)
  float h0=0,h1=0,h2=0,h3=0,h4=0,h5=0,h6=0,h7=0;
  int pos = 0;
  float* vb = vals + ((size_t)rowW * NCHUNK + cc) * CSLOT;

  __syncthreads();   // mcnt zero-init visible before any mirror atomic

#pragma unroll
  for (int t = 0; t < TILES; ++t) {
    const int colA = col0 + t * 32 + (l & 31);

    f32x16 acc;
#pragma unroll
    for (int r = 0; r < 16; ++r) acc[r] = 0.f;
    __builtin_amdgcn_s_setprio(1);
#pragma unroll
    for (int kk = 0; kk < 16; ++kk) {
      bf16x8 a = *(const bf16x8*)&ztq[(size_t)(kk * 2 + kg) * N_ + colA];  // direct, L1-shared
      acc = __builtin_amdgcn_mfma_f32_32x32x16_bf16(a, bf[kk], acc, 0, 0, 0);
    }
    __builtin_amdgcn_s_setprio(0);

    // scan into register slots (+ LDS mirror for column endpoint when off-diagonal)
    const uint32_t wsh = mW[t] >> (kg * 4);
#pragma unroll
    for (int r = 0; r < 16; ++r) {
      const int cpos = (r & 3) + 8 * (r >> 2);
      bool hit = ((((wsh >> cpos) & 1u) == 0u) && (acc[r] > THETA));
      if (__any(hit)) {
        if (hit) {
          INS8(h0,h1,h2,h3,h4,h5,h6,h7, pos, acc[r]);
          if (offdiag) {
            int jc = t * 32 + cpos + 4 * kg;          // local column 0..127
            int p = atomicAdd(&mcnt[jc], 1);
            if (p < 8) mcell[jc * 8 + p] = acc[r];
          }
        }
      }
    }
  }

  // ---- flush normal cells: predicated scalar stores (kg0 front, kg1 back) ----
  if (kg == 0) {
    if (pos > 0) vb[0] = h0;  if (pos > 1) vb[1] = h1;
    if (pos > 2) vb[2] = h2;  if (pos > 3) vb[3] = h3;
    if (pos > 4) vb[4] = h4;  if (pos > 5) vb[5] = h5;
    if (pos > 6) vb[6] = h6;  if (pos > 7) vb[7] = h7;
  } else {
    if (pos > 0) vb[7] = h0;  if (pos > 1) vb[6] = h1;
    if (pos > 2) vb[5] = h2;  if (pos > 3) vb[4] = h3;
    if (pos > 4) vb[3] = h4;  if (pos > 5) vb[2] = h5;
    if (pos > 6) vb[1] = h6;  if (pos > 7) vb[0] = h7;
  }
  counts[(rowW * NCHUNK + cc) * 2 + kg] = pos;

  // ---- flush mirror cells: LDS -> cells (col j, chunk rc) ----
  if (offdiag) {
    __syncthreads();   // all waves' mirror writes done
    int jc = tid >> 1, half = tid & 1;
    float4 m = *(float4*)&mcell[jc * 8 + half * 4];
    float* dm = vals + ((size_t)(col0 + jc) * NCHUNK + rc) * CSLOT + half * 4;
    *(float4*)dm = m;
    if (half == 0) {
      counts[((col0 + jc) * NCHUNK + rc) * 2 + 0] = mcnt[jc];
      counts[((col0 + jc) * NCHUNK + rc) * 2 + 1] = 0;
    }
  }
}

// ---------------- K3: finalize (1 wave/row): pos pick + top-10 of collected + loss ----------------
__global__ __launch_bounds__(256) void finalize_kernel(
    const float* __restrict__ feats, const int* __restrict__ labels,
    const float* __restrict__ inv_norm,
    const int* __restrict__ glist, const int* __restrict__ cnt_g,
    const int* __restrict__ counts, const float* __restrict__ vals,
    float* __restrict__ li, int* __restrict__ valid) {
  const int row = blockIdx.x * 4 + (threadIdx.x >> 6);
  const int lane = threadIdx.x & 63;
  const int lab = labels[row];
  const int gc = cnt_g[lab];
  const int gn = gc < GCAP ? gc : GCAP;
  const float4* feats4 = (const float4*)feats;

  // --- positive pick: threefry argmax over same-label (excl self) ---
  uint32_t bk = 0u; int bj = -1;
  for (int e = lane; e < gn; e += 64) {
    int j = glist[lab * GCAP + e];
    if (j != row) {
      uint32_t key = tf_bits((uint32_t)row * (uint32_t)N_ + (uint32_t)j) >> 9;
      if (bj < 0 || key > bk || (key == bk && j < bj)) { bk = key; bj = j; }
    }
  }
#pragma unroll
  for (int o = 32; o; o >>= 1) {
    uint32_t ok = __shfl_xor(bk, o);
    int oj = __shfl_xor(bj, o);
    if (oj >= 0 && (bj < 0 || ok > bk || (ok == bk && oj < bj))) { bk = ok; bj = oj; }
  }

  // --- exact fp32 positive cosine ---
  float pc = 0.f;
  if (bj >= 0) {
    float4 a = feats4[(size_t)row * 64 + lane];
    float4 b = feats4[(size_t)bj * 64 + lane];
    float p = a.x * b.x + a.y * b.y + a.z * b.z + a.w * b.w;
#pragma unroll
    for (int o = 32; o; o >>= 1) p += __shfl_xor(p, o);
    pc = p * inv_norm[row] * inv_norm[bj];
  }

  // --- load collected: 64 cells x 8 slots = 512, 8 per lane (coalesced) ---
  float vv[8];
  int ovf = 0;
#pragma unroll
  for (int q = 0; q < 8; ++q) {
    int s = lane + 64 * q;           // slot id 0..511
    int cell = s >> 3, wi = s & 7;   // chunk cell 0..63; front c0, back c1
    int c0 = counts[(row * NCHUNK + cell) * 2 + 0];
    int c1 = counts[(row * NCHUNK + cell) * 2 + 1];
    ovf |= (c0 + c1 > CSLOT) ? 1 : 0;
    float val = vals[(size_t)row * (NCHUNK * CSLOT) + s];
    int c1b = c1 < CSLOT ? c1 : CSLOT;
    bool live = (wi < c0) || (wi >= CSLOT - c1b);
    vv[q] = live ? val : -INFINITY;
  }

  float num = expf(pc * TEMP_INV);
  float den = num;
  int got = 0;
#pragma unroll 1
  for (int it = 0; it < HARDK; ++it) {
    float lm = fmaxf(fmaxf(fmaxf(vv[0], vv[1]), fmaxf(vv[2], vv[3])),
                     fmaxf(fmaxf(vv[4], vv[5]), fmaxf(vv[6], vv[7])));
    float wm = lm;
#pragma unroll
    for (int o = 32; o; o >>= 1) wm = fmaxf(wm, __shfl_xor(wm, o));
    if (wm < -1e37f) break;
    den += expf(wm * TEMP_INV);
    ++got;
    unsigned long long b = __ballot(lm == wm);
    int fl = __ffsll((long long)b) - 1;
    if (lane == fl) {
      if      (vv[0] == wm) vv[0] = -INFINITY;
      else if (vv[1] == wm) vv[1] = -INFINITY;
      else if (vv[2] == wm) vv[2] = -INFINITY;
      else if (vv[3] == wm) vv[3] = -INFINITY;
      else if (vv[4] == wm) vv[4] = -INFINITY;
      else if (vv[5] == wm) vv[5] = -INFINITY;
      else if (vv[6] == wm) vv[6] = -INFINITY;
      else                  vv[7] = -INFINITY;
    }
  }

  const int ndiff = N_ - gc;
  const bool vld = (bj >= 0) && (ndiff > 0);
  const int want = ndiff < HARDK ? ndiff : HARDK;

  // --- exact cooperative fallback (P ~ 4e-8/cell; guarantees exactness) ---
  if (vld && (__any(ovf) || got < want)) {
    float tk[HARDK];
#pragma unroll
    for (int k = 0; k < HARDK; ++k) tk[k] = -INFINITY;
    const float invr = inv_norm[row];
    const float4 a = feats4[(size_t)row * 64 + lane];   // whole row: 64 lanes x float4
#pragma unroll 1
    for (int j = 0; j < N_; ++j) {
      if (j == row || labels[j] == lab) continue;       // wave-uniform branch
      float4 b = feats4[(size_t)j * 64 + lane];
      float p = a.x * b.x + a.y * b.y + a.z * b.z + a.w * b.w;
#pragma unroll
      for (int o = 32; o; o >>= 1) p += __shfl_xor(p, o);
      float c = p * invr * inv_norm[j];                 // wave-uniform value
      if (c > tk[0]) {
        tk[0] = c;
#pragma unroll
        for (int q = 0; q < HARDK - 1; ++q)
          if (tk[q] > tk[q + 1]) { float tmp = tk[q]; tk[q] = tk[q + 1]; tk[q + 1] = tmp; }
      }
    }
    den = num;
#pragma unroll
    for (int k = 0; k < HARDK; ++k)
      if (tk[k] > -1e37f) den += expf(tk[k] * TEMP_INV);
  }

  float L = 0.f;
  if (vld) L = -logf(fmaxf(num / fmaxf(den, 1e-8f), 1e-8f));
  if (lane == 0) {
    li[row] = L;
    valid[row] = vld ? 1 : 0;
  }
}

// ---------------- K4: final mean ----------------
__global__ __launch_bounds__(256) void reduce_kernel(const float* __restrict__ li,
                                                     const int* __restrict__ valid,
                                                     float* __restrict__ out) {
  __shared__ float ssum[4];
  __shared__ int scnt[4];
  float s = 0.f; int c = 0;
  for (int i = threadIdx.x; i < N_; i += 256) { s += li[i]; c += valid[i]; }
#pragma unroll
  for (int o = 32; o; o >>= 1) { s += __shfl_down(s, o); c += __shfl_down(c, o); }
  if ((threadIdx.x & 63) == 0) { ssum[threadIdx.x >> 6] = s; scnt[threadIdx.x >> 6] = c; }
  __syncthreads();
  if (threadIdx.x == 0) {
    float S = 0.f; int C = 0;
    for (int w = 0; w < 4; ++w) { S += ssum[w]; C += scnt[w]; }
    out[0] = S / (float)(C > 0 ? C : 1);
  }
}

extern "C" void kernel_launch(void* const* d_in, const int* in_sizes, int n_in,
                              void* d_out, int out_size, void* d_ws, size_t ws_size,
                              hipStream_t stream) {
  const float* feats  = (const float*)d_in[0];
  const int*   labels = (const int*)d_in[1];
  float* out = (float*)d_out;

  char* w = (char*)d_ws;
  unsigned short* zt  = (unsigned short*)w;  w += (size_t)N_ * D_ * 2;        // 4 MB (K-major)
  float* inv_norm = (float*)w;               w += (size_t)N_ * 4;
  uint32_t* mask_g = (uint32_t*)w;           w += (size_t)NLBL * 256 * 4;     // 128 KB
  int* glist = (int*)w;                      w += (size_t)NLBL * GCAP * 4;    // 128 KB
  int* cnt_g = (int*)w;                      w += (size_t)NLBL * 4;
  int* counts = (int*)w;                     w += (size_t)N_ * NCHUNK * 2 * 4;        // 4 MB
  float* vals = (float*)w;                   w += (size_t)N_ * NCHUNK * CSLOT * 4;    // 16.8 MB
  float* li_arr = (float*)w;                 w += (size_t)N_ * 4;
  int* valid_arr = (int*)w;                  w += (size_t)N_ * 4;

  hipLaunchKernelGGL(prep_group_kernel, dim3(640), dim3(256), 0, stream,
                     feats, labels, inv_norm, zt, mask_g, glist, cnt_g);
  hipLaunchKernelGGL(collect_kernel, dim3(NTRI), dim3(256), 0, stream,
                     zt, labels, mask_g, vals, counts);
  hipLaunchKernelGGL(finalize_kernel, dim3(N_ / 4), dim3(256), 0, stream,
                     feats, labels, inv_norm, glist, cnt_g, counts, vals, li_arr, valid_arr);
  hipLaunchKernelGGL(reduce_kernel, dim3(1), dim3(256), 0, stream, li_arr, valid_arr, out);
}

// Round 22
// 87.974 us; speedup vs baseline: 1.1040x; 1.1040x over previous
//
#include <hip/hip_runtime.h>
#include <cstdint>
#include <math.h>

#define N_     8192
#define D_     256
#define NLBL   128
#define TEMP_INV 14.285714285714286f
#define HARDK  10
#define THETA  0.16f
#define GCAP   256              // per-label list capacity (mean 64, max ~104)

#define NCHUNK 64
#define CHUNK  (N_ / NCHUNK)    // 128 cols per chunk
#define TILES  (CHUNK / 32)     // 4
#define HALVES (TILES * 2)      // 8 half-K stages
#define CSLOT  8                // per-(row,chunk): kg0 fills front, kg1 fills back
#define NTRI   ((NCHUNK * (NCHUNK + 1)) / 2)   // 2080 = 8 * 260

typedef __attribute__((ext_vector_type(8)))  short bf16x8;
typedef __attribute__((ext_vector_type(16))) float f32x16;

// ---------------- Threefry-2x32, key=(0,42): exact-match validated R1-R21 ----------------
__device__ __forceinline__ uint32_t rotl32(uint32_t x, int n) {
  return (x << n) | (x >> (32 - n));
}
__device__ uint32_t tf_bits(uint32_t idx) {
  uint32_t x0 = 0u, x1 = idx;
  const uint32_t k0 = 0u, k1 = 42u;
  const uint32_t k2 = k0 ^ k1 ^ 0x1BD11BDAu;
  x0 += k0; x1 += k1;
#define TFR(r) { x0 += x1; x1 = rotl32(x1, r); x1 ^= x0; }
  TFR(13) TFR(15) TFR(26) TFR(6)
  x0 += k1; x1 += k2 + 1u;
  TFR(17) TFR(29) TFR(16) TFR(24)
  x0 += k2; x1 += k0 + 2u;
  TFR(13) TFR(15) TFR(26) TFR(6)
  x0 += k0; x1 += k1 + 3u;
  TFR(17) TFR(29) TFR(16) TFR(24)
  x0 += k1; x1 += k2 + 4u;
  TFR(13) TFR(15) TFR(26) TFR(6)
  x0 += k2; x1 += k0 + 5u;
#undef TFR
  return x0 ^ x1;
}

__device__ __forceinline__ uint32_t f2bf(float x) {  // RNE
  uint32_t b = __float_as_uint(x);
  return (b + 0x7FFFu + ((b >> 16) & 1u)) >> 16;
}

// ---------------- K1: fused prep (512 blocks x 16 rows) + mask/glist (32 blocks) -------
// Mask/glist build is single-pass: LDS atomicOr for mask words; glist via global
// atomicAdd on cnt_g (pre-zeroed by memset). List ORDER is nondeterministic, but the
// finalize argmax is (key,j)-max -> order-independent -> output bit-deterministic.
__global__ __launch_bounds__(256) void prep_group_kernel(
    const float* __restrict__ feats, const int* __restrict__ labels,
    float* __restrict__ inv_norm, unsigned short* __restrict__ zt,
    uint32_t* __restrict__ mask_g, int* __restrict__ glist, int* __restrict__ cnt_g) {
  const int tid = threadIdx.x;

  if (blockIdx.x < 512) {
    __shared__ uint4 tile[16][33];   // bf16 rows staged for transpose (+pad)
    const int row0 = blockIdx.x * 16;
    const int wv = tid >> 6, l = tid & 63;
#pragma unroll
    for (int rr = 0; rr < 4; ++rr) {
      const int rloc = wv * 4 + rr;
      const int row = row0 + rloc;
      float4 v = ((const float4*)feats)[(size_t)row * 64 + l];
      float ss = v.x * v.x + v.y * v.y + v.z * v.z + v.w * v.w;
#pragma unroll
      for (int o = 32; o; o >>= 1) ss += __shfl_xor(ss, o);
      float inv = 1.0f / fmaxf(sqrtf(ss), 1e-12f);
      if (l == 0) inv_norm[row] = inv;
      uint2 p;
      p.x = f2bf(v.x * inv) | (f2bf(v.y * inv) << 16);
      p.y = f2bf(v.z * inv) | (f2bf(v.w * inv) << 16);
      *(uint2*)((char*)&tile[0][0] + rloc * 528 + l * 8) = p;
    }
    __syncthreads();
#pragma unroll
    for (int it = 0; it < 2; ++it) {
      int idx = it * 256 + tid;          // 0..511
      int c = idx >> 4, r = idx & 15;    // consecutive tid -> consecutive r (256B seg)
      ((uint4*)zt)[(size_t)c * N_ + row0 + r] = tile[r][c];
    }
  } else {
    __shared__ uint32_t mlds[NLBL * 8];  // 4 KB: mask words for this 256-col span
    const int b = blockIdx.x - 512;      // 0..31
    const int c0 = b * 256;
#pragma unroll
    for (int it = 0; it < 4; ++it) mlds[it * 256 + tid] = 0u;
    __syncthreads();
    const int col = c0 + tid;
    const int lab = labels[col];
    atomicOr(&mlds[lab * 8 + ((col & 255) >> 5)], 1u << (col & 31));
    int p = atomicAdd(&cnt_g[lab], 1);
    if (p < GCAP) glist[lab * GCAP + p] = col;
    __syncthreads();
#pragma unroll
    for (int it = 0; it < 4; ++it) {
      int idx = it * 256 + tid;          // 0..1023
      int lb = idx >> 3, wd = idx & 7;
      mask_g[lb * 256 + (c0 >> 5) + wd] = mlds[idx];
    }
  }
}

// ---------------- K2: MFMA sim, triangle 128x128, half-K dbuf (20.5 KB -> 7 blk/CU) ----
__device__ __forceinline__ void stage_half(const unsigned short* zt, char (*AbK)[1024],
                                           int colT, int kh, int wid, int l, int kg) {
  // stage kk = kh*8 + (wid*2+q): plane (kk*2+kg), rows colT..+31 contiguous per half-wave
  const char* base = (const char*)zt + ((size_t)kg * N_ + colT + (l & 31)) * 16;
#pragma unroll
  for (int q = 0; q < 2; ++q) {
    const int kkloc = wid * 2 + q;
    const int kk = kh * 8 + kkloc;
    __builtin_amdgcn_global_load_lds(
        (const __attribute__((address_space(1))) void*)(base + (size_t)kk * (2 * N_ * 16)),
        (__attribute__((address_space(3))) void*)(&AbK[kkloc][0]), 16, 0, 0);
  }
}

#define INS8(H0,H1,H2,H3,H4,H5,H6,H7,POS,C) \
  { H0 = (POS==0)?(C):H0; H1 = (POS==1)?(C):H1; H2 = (POS==2)?(C):H2; H3 = (POS==3)?(C):H3; \
    H4 = (POS==4)?(C):H4; H5 = (POS==5)?(C):H5; H6 = (POS==6)?(C):H6; H7 = (POS==7)?(C):H7; \
    ++POS; }

__global__ __launch_bounds__(256) void collect_kernel(const unsigned short* __restrict__ zt,
                                                      const int* __restrict__ labels,
                                                      const uint32_t* __restrict__ mask_g,
                                                      float* __restrict__ vals,
                                                      int* __restrict__ counts) {
  __shared__ char Ab[2][8][1024];      // half-K double buffer, 16 KB
  __shared__ float mcell[128 * 8];     // mirror slots [col][8], 4 KB
  __shared__ int   mcnt[128];          // mirror counters, 0.5 KB

  const int tid = threadIdx.x;
  const int l = tid & 63, wid = tid >> 6;  // wid 0..3
  const int kg = l >> 5;

  // bijective XCD swizzle: 2080 = 8 * 260; each XCD gets 260 consecutive triangle blocks
  const int bid = (blockIdx.x & 7) * (NTRI / 8) + (blockIdx.x >> 3);

  // triangular decode: bid -> (rc, cc), rc <= cc (block-uniform scalar loop)
  int rc = 0, rem = bid;
  while (rem >= NCHUNK - rc) { rem -= NCHUNK - rc; ++rc; }
  const int cc = rc + rem;
  const bool offdiag = (cc > rc);

  const int row0 = rc * 128;
  const int col0 = cc * CHUNK;
  const int rowW = row0 + wid * 32 + (l & 31);
  const int lab = labels[rowW];

  if (tid < 128) mcnt[tid] = 0;

  // 4 tile-masks preloaded
  uint32_t mW[TILES];
  {
    uint4 m0 = *(const uint4*)(mask_g + lab * 256 + (col0 >> 5));
    mW[0] = m0.x; mW[1] = m0.y; mW[2] = m0.z; mW[3] = m0.w;
  }

  // B fragments from K-major planes: contiguous 512B per 32-lane half (AGPR-parked)
  bf16x8 bf[16];
  {
    const uint4* ztq = (const uint4*)zt;
#pragma unroll
    for (int kk = 0; kk < 16; ++kk)
      bf[kk] = *(const bf16x8*)&ztq[(size_t)(kk * 2 + kg) * N_ + rowW];
  }

  // normal-path hit slots in registers (static select-chain)
  float h0=0,h1=0,h2=0,h3=0,h4=0,h5=0,h6=0,h7=0;
  int pos = 0;
  float* vb = vals + ((size_t)rowW * NCHUNK + cc) * CSLOT;

  stage_half(zt, Ab[0], col0, 0, wid, l, kg);
  __syncthreads();   // stage(0) landed + mcnt zeroed visible

  f32x16 acc;
  int buf = 0;
#pragma unroll
  for (int h = 0; h < HALVES; ++h) {
    const int t = h >> 1, kh = h & 1;
    if (h + 1 < HALVES)
      stage_half(zt, Ab[buf ^ 1], col0 + ((h + 1) >> 1) * 32, (h + 1) & 1, wid, l, kg);

    if (kh == 0) {
#pragma unroll
      for (int r = 0; r < 16; ++r) acc[r] = 0.f;
    }
    __builtin_amdgcn_s_setprio(1);
#pragma unroll
    for (int kkloc = 0; kkloc < 8; ++kkloc) {
      bf16x8 a = *(const bf16x8*)&Ab[buf][kkloc][l * 16];
      acc = __builtin_amdgcn_mfma_f32_32x32x16_bf16(a, bf[kh * 8 + kkloc], acc, 0, 0, 0);
    }
    __builtin_amdgcn_s_setprio(0);

    if (kh == 1) {
      // scan into register slots (+ LDS mirror for column endpoint when off-diagonal)
      const uint32_t wsh = mW[t] >> (kg * 4);
#pragma unroll
      for (int r = 0; r < 16; ++r) {
        const int cpos = (r & 3) + 8 * (r >> 2);
        bool hit = ((((wsh >> cpos) & 1u) == 0u) && (acc[r] > THETA));
        if (__any(hit)) {
          if (hit) {
            INS8(h0,h1,h2,h3,h4,h5,h6,h7, pos, acc[r]);
            if (offdiag) {
              int jc = t * 32 + cpos + 4 * kg;          // local column 0..127
              int p = atomicAdd(&mcnt[jc], 1);
              if (p < 8) mcell[jc * 8 + p] = acc[r];
            }
          }
        }
      }
    }
    __syncthreads();   // stage(h+1) landed + all reads of buf done
    buf ^= 1;
  }

  // ---- flush normal cells: predicated scalar stores (kg0 front, kg1 back) ----
  if (kg == 0) {
    if (pos > 0) vb[0] = h0;  if (pos > 1) vb[1] = h1;
    if (pos > 2) vb[2] = h2;  if (pos > 3) vb[3] = h3;
    if (pos > 4) vb[4] = h4;  if (pos > 5) vb[5] = h5;
    if (pos > 6) vb[6] = h6;  if (pos > 7) vb[7] = h7;
  } else {
    if (pos > 0) vb[7] = h0;  if (pos > 1) vb[6] = h1;
    if (pos > 2) vb[5] = h2;  if (pos > 3) vb[4] = h3;
    if (pos > 4) vb[3] = h4;  if (pos > 5) vb[2] = h5;
    if (pos > 6) vb[1] = h6;  if (pos > 7) vb[0] = h7;
  }
  counts[(rowW * NCHUNK + cc) * 2 + kg] = pos;

  // ---- flush mirror cells: LDS -> cells (col j, chunk rc) ----
  if (offdiag) {
    int jc = tid >> 1, half = tid & 1;
    float4 m = *(float4*)&mcell[jc * 8 + half * 4];
    float* dm = vals + ((size_t)(col0 + jc) * NCHUNK + rc) * CSLOT + half * 4;
    *(float4*)dm = m;
    if (half == 0) {
      counts[((col0 + jc) * NCHUNK + rc) * 2 + 0] = mcnt[jc];
      counts[((col0 + jc) * NCHUNK + rc) * 2 + 1] = 0;
    }
  }
}

// ---------------- K3: finalize (1 wave/row): pos pick + top-10 of collected + loss ----------------
__global__ __launch_bounds__(256) void finalize_kernel(
    const float* __restrict__ feats, const int* __restrict__ labels,
    const float* __restrict__ inv_norm,
    const int* __restrict__ glist, const int* __restrict__ cnt_g,
    const int* __restrict__ counts, const float* __restrict__ vals,
    float* __restrict__ li, int* __restrict__ valid) {
  const int row = blockIdx.x * 4 + (threadIdx.x >> 6);
  const int lane = threadIdx.x & 63;
  const int lab = labels[row];
  const int gc = cnt_g[lab];
  const int gn = gc < GCAP ? gc : GCAP;
  const float4* feats4 = (const float4*)feats;

  // --- positive pick: threefry argmax over same-label (excl self); order-independent ---
  uint32_t bk = 0u; int bj = -1;
  for (int e = lane; e < gn; e += 64) {
    int j = glist[lab * GCAP + e];
    if (j != row) {
      uint32_t key = tf_bits((uint32_t)row * (uint32_t)N_ + (uint32_t)j) >> 9;
      if (bj < 0 || key > bk || (key == bk && j < bj)) { bk = key; bj = j; }
    }
  }
#pragma unroll
  for (int o = 32; o; o >>= 1) {
    uint32_t ok = __shfl_xor(bk, o);
    int oj = __shfl_xor(bj, o);
    if (oj >= 0 && (bj < 0 || ok > bk || (ok == bk && oj < bj))) { bk = ok; bj = oj; }
  }

  // --- exact fp32 positive cosine ---
  float pc = 0.f;
  if (bj >= 0) {
    float4 a = feats4[(size_t)row * 64 + lane];
    float4 b = feats4[(size_t)bj * 64 + lane];
    float p = a.x * b.x + a.y * b.y + a.z * b.z + a.w * b.w;
#pragma unroll
    for (int o = 32; o; o >>= 1) p += __shfl_xor(p, o);
    pc = p * inv_norm[row] * inv_norm[bj];
  }

  // --- load collected: 64 cells x 8 slots = 512, 8 per lane (coalesced) ---
  float vv[8];
  int ovf = 0;
#pragma unroll
  for (int q = 0; q < 8; ++q) {
    int s = lane + 64 * q;           // slot id 0..511
    int cell = s >> 3, wi = s & 7;   // chunk cell 0..63; front c0, back c1
    int c0 = counts[(row * NCHUNK + cell) * 2 + 0];
    int c1 = counts[(row * NCHUNK + cell) * 2 + 1];
    ovf |= (c0 + c1 > CSLOT) ? 1 : 0;
    float val = vals[(size_t)row * (NCHUNK * CSLOT) + s];
    int c1b = c1 < CSLOT ? c1 : CSLOT;
    bool live = (wi < c0) || (wi >= CSLOT - c1b);
    vv[q] = live ? val : -INFINITY;
  }

  float num = expf(pc * TEMP_INV);
  float den = num;
  int got = 0;
#pragma unroll 1
  for (int it = 0; it < HARDK; ++it) {
    float lm = fmaxf(fmaxf(fmaxf(vv[0], vv[1]), fmaxf(vv[2], vv[3])),
                     fmaxf(fmaxf(vv[4], vv[5]), fmaxf(vv[6], vv[7])));
    float wm = lm;
#pragma unroll
    for (int o = 32; o; o >>= 1) wm = fmaxf(wm, __shfl_xor(wm, o));
    if (wm < -1e37f) break;
    den += expf(wm * TEMP_INV);
    ++got;
    unsigned long long b = __ballot(lm == wm);
    int fl = __ffsll((long long)b) - 1;
    if (lane == fl) {
      if      (vv[0] == wm) vv[0] = -INFINITY;
      else if (vv[1] == wm) vv[1] = -INFINITY;
      else if (vv[2] == wm) vv[2] = -INFINITY;
      else if (vv[3] == wm) vv[3] = -INFINITY;
      else if (vv[4] == wm) vv[4] = -INFINITY;
      else if (vv[5] == wm) vv[5] = -INFINITY;
      else if (vv[6] == wm) vv[6] = -INFINITY;
      else                  vv[7] = -INFINITY;
    }
  }

  const int ndiff = N_ - gc;
  const bool vld = (bj >= 0) && (ndiff > 0);
  const int want = ndiff < HARDK ? ndiff : HARDK;

  // --- exact cooperative fallback (P ~ 4e-8/cell; guarantees exactness) ---
  if (vld && (__any(ovf) || got < want)) {
    float tk[HARDK];
#pragma unroll
    for (int k = 0; k < HARDK; ++k) tk[k] = -INFINITY;
    const float invr = inv_norm[row];
    const float4 a = feats4[(size_t)row * 64 + lane];   // whole row: 64 lanes x float4
#pragma unroll 1
    for (int j = 0; j < N_; ++j) {
      if (j == row || labels[j] == lab) continue;       // wave-uniform branch
      float4 b = feats4[(size_t)j * 64 + lane];
      float p = a.x * b.x + a.y * b.y + a.z * b.z + a.w * b.w;
#pragma unroll
      for (int o = 32; o; o >>= 1) p += __shfl_xor(p, o);
      float c = p * invr * inv_norm[j];                 // wave-uniform value
      if (c > tk[0]) {
        tk[0] = c;
#pragma unroll
        for (int q = 0; q < HARDK - 1; ++q)
          if (tk[q] > tk[q + 1]) { float tmp = tk[q]; tk[q] = tk[q + 1]; tk[q + 1] = tmp; }
      }
    }
    den = num;
#pragma unroll
    for (int k = 0; k < HARDK; ++k)
      if (tk[k] > -1e37f) den += expf(tk[k] * TEMP_INV);
  }

  float L = 0.f;
  if (vld) L = -logf(fmaxf(num / fmaxf(den, 1e-8f), 1e-8f));
  if (lane == 0) {
    li[row] = L;
    valid[row] = vld ? 1 : 0;
  }
}

// ---------------- K4: final mean ----------------
__global__ __launch_bounds__(256) void reduce_kernel(const float* __restrict__ li,
                                                     const int* __restrict__ valid,
                                                     float* __restrict__ out) {
  __shared__ float ssum[4];
  __shared__ int scnt[4];
  float s = 0.f; int c = 0;
  for (int i = threadIdx.x; i < N_; i += 256) { s += li[i]; c += valid[i]; }
#pragma unroll
  for (int o = 32; o; o >>= 1) { s += __shfl_down(s, o); c += __shfl_down(c, o); }
  if ((threadIdx.x & 63) == 0) { ssum[threadIdx.x >> 6] = s; scnt[threadIdx.x >> 6] = c; }
  __syncthreads();
  if (threadIdx.x == 0) {
    float S = 0.f; int C = 0;
    for (int w = 0; w < 4; ++w) { S += ssum[w]; C += scnt[w]; }
    out[0] = S / (float)(C > 0 ? C : 1);
  }
}

extern "C" void kernel_launch(void* const* d_in, const int* in_sizes, int n_in,
                              void* d_out, int out_size, void* d_ws, size_t ws_size,
                              hipStream_t stream) {
  const float* feats  = (const float*)d_in[0];
  const int*   labels = (const int*)d_in[1];
  float* out = (float*)d_out;

  char* w = (char*)d_ws;
  unsigned short* zt  = (unsigned short*)w;  w += (size_t)N_ * D_ * 2;        // 4 MB (K-major)
  float* inv_norm = (float*)w;               w += (size_t)N_ * 4;
  uint32_t* mask_g = (uint32_t*)w;           w += (size_t)NLBL * 256 * 4;     // 128 KB
  int* glist = (int*)w;                      w += (size_t)NLBL * GCAP * 4;    // 128 KB
  int* cnt_g = (int*)w;                      w += (size_t)NLBL * 4;
  int* counts = (int*)w;                     w += (size_t)N_ * NCHUNK * 2 * 4;        // 4 MB
  float* vals = (float*)w;                   w += (size_t)N_ * NCHUNK * CSLOT * 4;    // 16.8 MB
  float* li_arr = (float*)w;                 w += (size_t)N_ * 4;
  int* valid_arr = (int*)w;                  w += (size_t)N_ * 4;

  hipMemsetAsync(cnt_g, 0, NLBL * sizeof(int), stream);
  hipLaunchKernelGGL(prep_group_kernel, dim3(544), dim3(256), 0, stream,
                     feats, labels, inv_norm, zt, mask_g, glist, cnt_g);
  hipLaunchKernelGGL(collect_kernel, dim3(NTRI), dim3(256), 0, stream,
                     zt, labels, mask_g, vals, counts);
  hipLaunchKernelGGL(finalize_kernel, dim3(N_ / 4), dim3(256), 0, stream,
                     feats, labels, inv_norm, glist, cnt_g, counts, vals, li_arr, valid_arr);
  hipLaunchKernelGGL(reduce_kernel, dim3(1), dim3(256), 0, stream, li_arr, valid_arr, out);
}

// Round 23
// 82.269 us; speedup vs baseline: 1.1806x; 1.0693x over previous
//
#include <hip/hip_runtime.h>
#include <cstdint>
#include <math.h>

#define N_     8192
#define D_     256
#define NLBL   128
#define TEMP_INV 14.285714285714286f
#define HARDK  10
#define THETA  0.16f
#define GCAP   256              // per-label list capacity (mean 64, max ~104)

#define NCHUNK 64
#define CHUNK  (N_ / NCHUNK)    // 128 cols per chunk
#define TILES  (CHUNK / 32)     // 4
#define CSLOT  8                // per-(row,chunk): kg0 fills front, kg1 fills back
#define NTRI   ((NCHUNK * (NCHUNK + 1)) / 2)   // 2080 = 8 * 260

typedef __attribute__((ext_vector_type(8)))  short bf16x8;
typedef __attribute__((ext_vector_type(16))) float f32x16;

// ---------------- Threefry-2x32, key=(0,42): exact-match validated R1-R22 ----------------
__device__ __forceinline__ uint32_t rotl32(uint32_t x, int n) {
  return (x << n) | (x >> (32 - n));
}
__device__ uint32_t tf_bits(uint32_t idx) {
  uint32_t x0 = 0u, x1 = idx;
  const uint32_t k0 = 0u, k1 = 42u;
  const uint32_t k2 = k0 ^ k1 ^ 0x1BD11BDAu;
  x0 += k0; x1 += k1;
#define TFR(r) { x0 += x1; x1 = rotl32(x1, r); x1 ^= x0; }
  TFR(13) TFR(15) TFR(26) TFR(6)
  x0 += k1; x1 += k2 + 1u;
  TFR(17) TFR(29) TFR(16) TFR(24)
  x0 += k2; x1 += k0 + 2u;
  TFR(13) TFR(15) TFR(26) TFR(6)
  x0 += k0; x1 += k1 + 3u;
  TFR(17) TFR(29) TFR(16) TFR(24)
  x0 += k1; x1 += k2 + 4u;
  TFR(13) TFR(15) TFR(26) TFR(6)
  x0 += k2; x1 += k0 + 5u;
#undef TFR
  return x0 ^ x1;
}

__device__ __forceinline__ uint32_t f2bf(float x) {  // RNE
  uint32_t b = __float_as_uint(x);
  return (b + 0x7FFFu + ((b >> 16) & 1u)) >> 16;
}

// ---------------- K1: fused prep (512 blocks x 16 rows) + group masks (128 blocks) -----
__global__ __launch_bounds__(256) void prep_group_kernel(
    const float* __restrict__ feats, const int* __restrict__ labels,
    float* __restrict__ inv_norm, unsigned short* __restrict__ zt,
    uint32_t* __restrict__ mask_g, int* __restrict__ glist, int* __restrict__ cnt_g) {
  __shared__ uint4 tile[16][33];   // bf16 rows staged for transpose (+pad)
  __shared__ int lcnt;
  const int tid = threadIdx.x;

  if (blockIdx.x < 512) {
    const int row0 = blockIdx.x * 16;
    const int wv = tid >> 6, l = tid & 63;
#pragma unroll
    for (int rr = 0; rr < 4; ++rr) {
      const int rloc = wv * 4 + rr;
      const int row = row0 + rloc;
      float4 v = ((const float4*)feats)[(size_t)row * 64 + l];
      float ss = v.x * v.x + v.y * v.y + v.z * v.z + v.w * v.w;
#pragma unroll
      for (int o = 32; o; o >>= 1) ss += __shfl_xor(ss, o);
      float inv = 1.0f / fmaxf(sqrtf(ss), 1e-12f);
      if (l == 0) inv_norm[row] = inv;
      uint2 p;
      p.x = f2bf(v.x * inv) | (f2bf(v.y * inv) << 16);
      p.y = f2bf(v.z * inv) | (f2bf(v.w * inv) << 16);
      *(uint2*)((char*)&tile[0][0] + rloc * 528 + l * 8) = p;
    }
    __syncthreads();
#pragma unroll
    for (int it = 0; it < 2; ++it) {
      int idx = it * 256 + tid;          // 0..511
      int c = idx >> 4, r = idx & 15;    // consecutive tid -> consecutive r (256B seg)
      ((uint4*)zt)[(size_t)c * N_ + row0 + r] = tile[r][c];
    }
  } else {
    const int b = blockIdx.x - 512;
    const int lane = tid & 63, wv = tid >> 6;
    if (tid == 0) lcnt = 0;
    __syncthreads();
    for (int it = 0; it < N_; it += 256) {
      int col = it + tid;
      bool pred = (labels[col] == b);
      unsigned long long m = __ballot(pred);
      if (lane == 0) {
        int w0 = (it + wv * 64) >> 5;
        mask_g[b * 256 + w0]     = (uint32_t)m;
        mask_g[b * 256 + w0 + 1] = (uint32_t)(m >> 32);
      }
      if (pred) {
        int p = atomicAdd(&lcnt, 1);
        if (p < GCAP) glist[b * GCAP + p] = col;
      }
    }
    __syncthreads();
    if (tid == 0) cnt_g[b] = lcnt;
  }
}

// ---------------- K2: MFMA sim, triangle 128x128, double-buffer + XCD swizzle ----------
__device__ __forceinline__ void stage_tile(const unsigned short* zt, char (*AbK)[1024],
                                           int colT, int wid, int l, int kg) {
  // plane (kk*2+kg), rows colT..colT+31 contiguous per 32-lane half
  const char* base = (const char*)zt + ((size_t)kg * N_ + colT + (l & 31)) * 16;
#pragma unroll
  for (int q = 0; q < 4; ++q) {
    const int kk = wid * 4 + q;
    __builtin_amdgcn_global_load_lds(
        (const __attribute__((address_space(1))) void*)(base + (size_t)kk * (2 * N_ * 16)),
        (__attribute__((address_space(3))) void*)(&AbK[kk][0]), 16, 0, 0);
  }
}

#define INS8(H0,H1,H2,H3,H4,H5,H6,H7,POS,C) \
  { H0 = (POS==0)?(C):H0; H1 = (POS==1)?(C):H1; H2 = (POS==2)?(C):H2; H3 = (POS==3)?(C):H3; \
    H4 = (POS==4)?(C):H4; H5 = (POS==5)?(C):H5; H6 = (POS==6)?(C):H6; H7 = (POS==7)?(C):H7; \
    ++POS; }

__global__ __launch_bounds__(256) void collect_kernel(const unsigned short* __restrict__ zt,
                                                      const int* __restrict__ labels,
                                                      const uint32_t* __restrict__ mask_g,
                                                      float* __restrict__ vals,
                                                      int* __restrict__ counts) {
  __shared__ char Ab[2][16][1024];     // double buffer, 32 KB
  __shared__ float mcell[128 * 8];     // mirror slots [col][8], 4 KB
  __shared__ int   mcnt[128];          // mirror counters, 0.5 KB

  const int tid = threadIdx.x;
  const int l = tid & 63, wid = tid >> 6;  // wid 0..3
  const int kg = l >> 5;

  // bijective XCD swizzle: 2080 = 8 * 260; each XCD gets 260 consecutive triangle blocks
  const int bid = (blockIdx.x & 7) * (NTRI / 8) + (blockIdx.x >> 3);

  // triangular decode: bid -> (rc, cc), rc <= cc (block-uniform scalar loop)
  int rc = 0, rem = bid;
  while (rem >= NCHUNK - rc) { rem -= NCHUNK - rc; ++rc; }
  const int cc = rc + rem;
  const bool offdiag = (cc > rc);

  const int row0 = rc * 128;
  const int col0 = cc * CHUNK;
  const int rowW = row0 + wid * 32 + (l & 31);
  const int lab = labels[rowW];

  if (tid < 128) mcnt[tid] = 0;

  // 4 tile-masks preloaded
  uint32_t mW[TILES];
  {
    uint4 m0 = *(const uint4*)(mask_g + lab * 256 + (col0 >> 5));
    mW[0] = m0.x; mW[1] = m0.y; mW[2] = m0.z; mW[3] = m0.w;
  }

  // B fragments from K-major planes: contiguous 512B per 32-lane half
  bf16x8 bf[16];
  {
    const uint4* ztq = (const uint4*)zt;
#pragma unroll
    for (int kk = 0; kk < 16; ++kk)
      bf[kk] = *(const bf16x8*)&ztq[(size_t)(kk * 2 + kg) * N_ + rowW];
  }

  // normal-path hit slots in registers (static select-chain)
  float h0=0,h1=0,h2=0,h3=0,h4=0,h5=0,h6=0,h7=0;
  int pos = 0;
  float* vb = vals + ((size_t)rowW * NCHUNK + cc) * CSLOT;

  stage_tile(zt, Ab[0], col0, wid, l, kg);
  __syncthreads();

  int buf = 0;
#pragma unroll
  for (int t = 0; t < TILES; ++t) {
    if (t + 1 < TILES) stage_tile(zt, Ab[buf ^ 1], col0 + (t + 1) * 32, wid, l, kg);

    f32x16 acc;
#pragma unroll
    for (int r = 0; r < 16; ++r) acc[r] = 0.f;
    __builtin_amdgcn_s_setprio(1);
#pragma unroll
    for (int kk = 0; kk < 16; ++kk) {
      bf16x8 a = *(const bf16x8*)&Ab[buf][kk][l * 16];
      acc = __builtin_amdgcn_mfma_f32_32x32x16_bf16(a, bf[kk], acc, 0, 0, 0);
    }
    __builtin_amdgcn_s_setprio(0);

    // scan into register slots (+ LDS mirror for column endpoint when off-diagonal)
    const uint32_t wsh = mW[t] >> (kg * 4);
#pragma unroll
    for (int r = 0; r < 16; ++r) {
      const int cpos = (r & 3) + 8 * (r >> 2);
      bool hit = ((((wsh >> cpos) & 1u) == 0u) && (acc[r] > THETA));
      if (__any(hit)) {
        if (hit) {
          INS8(h0,h1,h2,h3,h4,h5,h6,h7, pos, acc[r]);
          if (offdiag) {
            int jc = t * 32 + cpos + 4 * kg;          // local column 0..127
            int p = atomicAdd(&mcnt[jc], 1);
            if (p < 8) mcell[jc * 8 + p] = acc[r];
          }
        }
      }
    }
    __syncthreads();   // stage(t+1) landed + all LDS writes/reads of buf done
    buf ^= 1;
  }

  // ---- flush normal cells: predicated scalar stores (kg0 front, kg1 back) ----
  if (kg == 0) {
    if (pos > 0) vb[0] = h0;  if (pos > 1) vb[1] = h1;
    if (pos > 2) vb[2] = h2;  if (pos > 3) vb[3] = h3;
    if (pos > 4) vb[4] = h4;  if (pos > 5) vb[5] = h5;
    if (pos > 6) vb[6] = h6;  if (pos > 7) vb[7] = h7;
  } else {
    if (pos > 0) vb[7] = h0;  if (pos > 1) vb[6] = h1;
    if (pos > 2) vb[5] = h2;  if (pos > 3) vb[4] = h3;
    if (pos > 4) vb[3] = h4;  if (pos > 5) vb[2] = h5;
    if (pos > 6) vb[1] = h6;  if (pos > 7) vb[0] = h7;
  }
  counts[(rowW * NCHUNK + cc) * 2 + kg] = pos;

  // ---- flush mirror cells: LDS -> cells (col j, chunk rc) ----
  if (offdiag) {
    int jc = tid >> 1, half = tid & 1;
    float4 m = *(float4*)&mcell[jc * 8 + half * 4];
    float* dm = vals + ((size_t)(col0 + jc) * NCHUNK + rc) * CSLOT + half * 4;
    *(float4*)dm = m;
    if (half == 0) {
      counts[((col0 + jc) * NCHUNK + rc) * 2 + 0] = mcnt[jc];
      counts[((col0 + jc) * NCHUNK + rc) * 2 + 1] = 0;
    }
  }
}

// ---------------- K3: finalize (1 wave = 1 row = 1 block; 8192 blocks for packing) -----
__global__ __launch_bounds__(64) void finalize_kernel(
    const float* __restrict__ feats, const int* __restrict__ labels,
    const float* __restrict__ inv_norm,
    const int* __restrict__ glist, const int* __restrict__ cnt_g,
    const int* __restrict__ counts, const float* __restrict__ vals,
    float* __restrict__ li, int* __restrict__ valid) {
  const int row = blockIdx.x;
  const int lane = threadIdx.x & 63;
  const int lab = labels[row];
  const int gc = cnt_g[lab];
  const int gn = gc < GCAP ? gc : GCAP;
  const float4* feats4 = (const float4*)feats;

  // --- positive pick: threefry argmax over same-label (excl self) ---
  uint32_t bk = 0u; int bj = -1;
  for (int e = lane; e < gn; e += 64) {
    int j = glist[lab * GCAP + e];
    if (j != row) {
      uint32_t key = tf_bits((uint32_t)row * (uint32_t)N_ + (uint32_t)j) >> 9;
      if (bj < 0 || key > bk || (key == bk && j < bj)) { bk = key; bj = j; }
    }
  }
#pragma unroll
  for (int o = 32; o; o >>= 1) {
    uint32_t ok = __shfl_xor(bk, o);
    int oj = __shfl_xor(bj, o);
    if (oj >= 0 && (bj < 0 || ok > bk || (ok == bk && oj < bj))) { bk = ok; bj = oj; }
  }

  // --- exact fp32 positive cosine ---
  float pc = 0.f;
  if (bj >= 0) {
    float4 a = feats4[(size_t)row * 64 + lane];
    float4 b = feats4[(size_t)bj * 64 + lane];
    float p = a.x * b.x + a.y * b.y + a.z * b.z + a.w * b.w;
#pragma unroll
    for (int o = 32; o; o >>= 1) p += __shfl_xor(p, o);
    pc = p * inv_norm[row] * inv_norm[bj];
  }

  // --- load collected: 64 cells x 8 slots = 512, 8 per lane (coalesced) ---
  float vv[8];
  int ovf = 0;
#pragma unroll
  for (int q = 0; q < 8; ++q) {
    int s = lane + 64 * q;           // slot id 0..511
    int cell = s >> 3, wi = s & 7;   // chunk cell 0..63; front c0, back c1
    int c0 = counts[(row * NCHUNK + cell) * 2 + 0];
    int c1 = counts[(row * NCHUNK + cell) * 2 + 1];
    ovf |= (c0 + c1 > CSLOT) ? 1 : 0;
    float val = vals[(size_t)row * (NCHUNK * CSLOT) + s];
    int c1b = c1 < CSLOT ? c1 : CSLOT;
    bool live = (wi < c0) || (wi >= CSLOT - c1b);
    vv[q] = live ? val : -INFINITY;
  }

  float num = expf(pc * TEMP_INV);
  float den = num;
  int got = 0;
#pragma unroll 1
  for (int it = 0; it < HARDK; ++it) {
    float lm = fmaxf(fmaxf(fmaxf(vv[0], vv[1]), fmaxf(vv[2], vv[3])),
                     fmaxf(fmaxf(vv[4], vv[5]), fmaxf(vv[6], vv[7])));
    float wm = lm;
#pragma unroll
    for (int o = 32; o; o >>= 1) wm = fmaxf(wm, __shfl_xor(wm, o));
    if (wm < -1e37f) break;
    den += expf(wm * TEMP_INV);
    ++got;
    unsigned long long b = __ballot(lm == wm);
    int fl = __ffsll((long long)b) - 1;
    if (lane == fl) {
      if      (vv[0] == wm) vv[0] = -INFINITY;
      else if (vv[1] == wm) vv[1] = -INFINITY;
      else if (vv[2] == wm) vv[2] = -INFINITY;
      else if (vv[3] == wm) vv[3] = -INFINITY;
      else if (vv[4] == wm) vv[4] = -INFINITY;
      else if (vv[5] == wm) vv[5] = -INFINITY;
      else if (vv[6] == wm) vv[6] = -INFINITY;
      else                  vv[7] = -INFINITY;
    }
  }

  const int ndiff = N_ - gc;
  const bool vld = (bj >= 0) && (ndiff > 0);
  const int want = ndiff < HARDK ? ndiff : HARDK;

  // --- exact cooperative fallback (P ~ 4e-8/cell; guarantees exactness) ---
  if (vld && (__any(ovf) || got < want)) {
    float tk[HARDK];
#pragma unroll
    for (int k = 0; k < HARDK; ++k) tk[k] = -INFINITY;
    const float invr = inv_norm[row];
    const float4 a = feats4[(size_t)row * 64 + lane];   // whole row: 64 lanes x float4
#pragma unroll 1
    for (int j = 0; j < N_; ++j) {
      if (j == row || labels[j] == lab) continue;       // wave-uniform branch
      float4 b = feats4[(size_t)j * 64 + lane];
      float p = a.x * b.x + a.y * b.y + a.z * b.z + a.w * b.w;
#pragma unroll
      for (int o = 32; o; o >>= 1) p += __shfl_xor(p, o);
      float c = p * invr * inv_norm[j];                 // wave-uniform value
      if (c > tk[0]) {
        tk[0] = c;
#pragma unroll
        for (int q = 0; q < HARDK - 1; ++q)
          if (tk[q] > tk[q + 1]) { float tmp = tk[q]; tk[q] = tk[q + 1]; tk[q + 1] = tmp; }
      }
    }
    den = num;
#pragma unroll
    for (int k = 0; k < HARDK; ++k)
      if (tk[k] > -1e37f) den += expf(tk[k] * TEMP_INV);
  }

  float L = 0.f;
  if (vld) L = -logf(fmaxf(num / fmaxf(den, 1e-8f), 1e-8f));
  if (lane == 0) {
    li[row] = L;
    valid[row] = vld ? 1 : 0;
  }
}

// ---------------- K4: final mean ----------------
__global__ __launch_bounds__(256) void reduce_kernel(const float* __restrict__ li,
                                                     const int* __restrict__ valid,
                                                     float* __restrict__ out) {
  __shared__ float ssum[4];
  __shared__ int scnt[4];
  float s = 0.f; int c = 0;
  for (int i = threadIdx.x; i < N_; i += 256) { s += li[i]; c += valid[i]; }
#pragma unroll
  for (int o = 32; o; o >>= 1) { s += __shfl_down(s, o); c += __shfl_down(c, o); }
  if ((threadIdx.x & 63) == 0) { ssum[threadIdx.x >> 6] = s; scnt[threadIdx.x >> 6] = c; }
  __syncthreads();
  if (threadIdx.x == 0) {
    float S = 0.f; int C = 0;
    for (int w = 0; w < 4; ++w) { S += ssum[w]; C += scnt[w]; }
    out[0] = S / (float)(C > 0 ? C : 1);
  }
}

extern "C" void kernel_launch(void* const* d_in, const int* in_sizes, int n_in,
                              void* d_out, int out_size, void* d_ws, size_t ws_size,
                              hipStream_t stream) {
  const float* feats  = (const float*)d_in[0];
  const int*   labels = (const int*)d_in[1];
  float* out = (float*)d_out;

  char* w = (char*)d_ws;
  unsigned short* zt  = (unsigned short*)w;  w += (size_t)N_ * D_ * 2;        // 4 MB (K-major)
  float* inv_norm = (float*)w;               w += (size_t)N_ * 4;
  uint32_t* mask_g = (uint32_t*)w;           w += (size_t)NLBL * 256 * 4;     // 128 KB
  int* glist = (int*)w;                      w += (size_t)NLBL * GCAP * 4;    // 128 KB
  int* cnt_g = (int*)w;                      w += (size_t)NLBL * 4;
  int* counts = (int*)w;                     w += (size_t)N_ * NCHUNK * 2 * 4;        // 4 MB
  float* vals = (float*)w;                   w += (size_t)N_ * NCHUNK * CSLOT * 4;    // 16.8 MB
  float* li_arr = (float*)w;                 w += (size_t)N_ * 4;
  int* valid_arr = (int*)w;                  w += (size_t)N_ * 4;

  hipLaunchKernelGGL(prep_group_kernel, dim3(640), dim3(256), 0, stream,
                     feats, labels, inv_norm, zt, mask_g, glist, cnt_g);
  hipLaunchKernelGGL(collect_kernel, dim3(NTRI), dim3(256), 0, stream,
                     zt, labels, mask_g, vals, counts);
  hipLaunchKernelGGL(finalize_kernel, dim3(N_), dim3(64), 0, stream,
                     feats, labels, inv_norm, glist, cnt_g, counts, vals, li_arr, valid_arr);
  hipLaunchKernelGGL(reduce_kernel, dim3(1), dim3(256), 0, stream, li_arr, valid_arr, out);
}